// Round 15
// baseline (16.252 us; speedup 1.0000x reference)
//
#include <hip/hip_runtime.h>

namespace {
constexpr int GS = 128;
constexpr int NPTS = GS * GS;          // 16384 points per grid
constexpr float RES = 0.25f;
constexpr int NGRIDS = 16;
constexpr int BLOCK = 1024;
constexpr int ROWS_PER_BLOCK = BLOCK / GS;     // 8 query rows per block
constexpr int CHUNKS = NPTS / BLOCK;           // 16 chunks per (grid,dir)
constexpr int NBLOCKS = NGRIDS * 2 * CHUNKS;   // 512
constexpr int SLAB_ROWS = 14;                  // max rows a block's windows touch
}

// R13 structure restored (best known: 15.7 us; R14's fused election was
// unfixably init-dependent — reverted). ONE change vs R13: the za = A[i]
// global load is issued BEFORE the staging loop, so its latency hides under
// the staging burst + barrier instead of sitting on phase-A's critical path
// (__syncthreads is a conservative codegen barrier; the compiler won't hoist
// a global load across it).
// Phase A: 7-row x 8-col SUPERSET window (ds_read_b64 pairs) at clamped base
// — always in-grid, covers every in-grid cell at Chebyshev radius <= 3.
// Exact-done iff best <= (4*RES)^2 = 1.0. Phase B: wave-cooperative straggler
// scan from GLOBAL memory (~2e-5/query at thr=1.0; R11 proved tighter thr
// explodes the event rate); one pass with K >= ceil(sqrt(bestA)/RES) is exact.
__global__ __launch_bounds__(BLOCK, 8) void chamfer_kernel(
    const float* __restrict__ pred, const float* __restrict__ gt,
    float* __restrict__ partial)
{
    __shared__ float slab[SLAB_ROWS * GS];     // 7168 B

    const int bid = blockIdx.x;
    const int chunk = bid & (CHUNKS - 1);
    const int pair = bid >> 4;             // CHUNKS = 16
    const int g = pair >> 1;
    const int dir = pair & 1;
    const float* __restrict__ A  = (dir == 0) ? gt + g * NPTS : pred + g * NPTS;
    const float* __restrict__ DB = (dir == 0) ? pred + g * NPTS : gt + g * NPTS;

    const int tid = threadIdx.x;
    const int i = chunk * BLOCK + tid;
    const float za = A[i];                 // issued BEFORE staging: latency
                                           // hides under the staging burst
    const int r0 = chunk * ROWS_PER_BLOCK;
    const int rlo = max(r0 - 3, 0);
    const int rhi = min(r0 + ROWS_PER_BLOCK + 2, GS - 1);  // r0+7 rows, +3 window
    const int nrow = rhi - rlo + 1;                        // <= 14

    // stage slab rows [rlo..rhi] as float4s: <=448 loads, fully coalesced
    if (tid < nrow * (GS / 4)) {
        const int row = tid >> 5;          // GS/4 = 32 quads per row
        const int c4  = tid & 31;
        reinterpret_cast<float4*>(slab)[tid] =
            reinterpret_cast<const float4*>(DB + (rlo + row) * GS)[c4];
    }
    __syncthreads();

    const int ri = r0 + (tid >> 7);
    const int ci = tid & (GS - 1);

    // superset window: clamp the BASE, not each cell
    const int rb = min(max(ri, 3), GS - 4);
    const int cb = min(max(ci, 3), GS - 4);
    const int cE = min((cb - 3) & ~1, GS - 8);      // even, 8 cols all in-grid
    const float* __restrict__ wbase = slab + (rb - 3 - rlo) * GS + cE;

    // per-axis planar terms
    float dx2[7];
    #pragma unroll
    for (int t = 0; t < 7; ++t) {
        const float dx = (float)(ri - (rb - 3 + t)) * RES;
        dx2[t] = dx * dx;
    }
    float dy2[8];
    #pragma unroll
    for (int t = 0; t < 8; ++t) {
        const float dy = (float)(ci - (cE + t)) * RES;
        dy2[t] = dy * dy;
    }

    // phase A: 7 rows x 4 ds_read_b64 (8 cols); per-row min fold
    float bacc[4] = {1e30f, 1e30f, 1e30f, 1e30f};
    #pragma unroll
    for (int a = 0; a < 7; ++a) {
        const float2* rp = reinterpret_cast<const float2*>(wbase + a * GS);
        float rm0 = 1e30f, rm1 = 1e30f;
        #pragma unroll
        for (int t = 0; t < 4; ++t) {
            const float2 z2 = rp[t];                // ds_read_b64, imm offset
            const float d0 = za - z2.x;
            const float d1 = za - z2.y;
            rm0 = fminf(rm0, fmaf(d0, d0, dy2[2 * t]));
            rm1 = fminf(rm1, fmaf(d1, d1, dy2[2 * t + 1]));
        }
        bacc[a & 3] = fminf(bacc[a & 3], fminf(rm0, rm1) + dx2[a]);
    }
    float best = fminf(fminf(bacc[0], bacc[1]), fminf(bacc[2], bacc[3]));

    // phase B: wave-cooperative straggler finish (rare), from global
    const int lane = tid & 63;
    const int lr = lane >> 3, lc = lane & 7;   // 8x8 lane tile
    unsigned long long pend = __ballot(best > 1.0f);
    while (pend) {
        const int src = __ffsll(pend) - 1;
        pend &= pend - 1;
        const int qri = __shfl(ri, src);
        const int qci = __shfl(ci, src);
        const float qza = __shfl(za, src);
        const float qb  = __shfl(best, src);
        int K = (int)(4.0f * sqrtf(qb)) + 1;   // >= ceil(sqrt(qb)/RES)
        K = min(K, GS - 1);
        float m = 1e30f;
        for (int tr = -K; tr <= K; tr += 8) {
            const int dr = tr + lr;
            if (dr > K) continue;
            const int r = min(max(qri + dr, 0), GS - 1);
            const float dx = (float)(qri - r) * RES;
            const float dxx2 = dx * dx;
            const float* __restrict__ row = DB + r * GS;
            for (int tc = -K; tc <= K; tc += 8) {
                const int dc = tc + lc;
                if (dc > K) continue;
                const int c = min(max(qci + dc, 0), GS - 1);
                const float dy = (float)(qci - c) * RES;
                const float dz = qza - row[c];
                m = fminf(m, fmaf(dz, dz, fmaf(dy, dy, dxx2)));
            }
        }
        #pragma unroll
        for (int off = 32; off > 0; off >>= 1) m = fminf(m, __shfl_xor(m, off));
        if (lane == src) best = fminf(best, m);
    }

    // block sum-reduction -> one partial per block (no atomics)
    for (int off = 32; off > 0; off >>= 1) best += __shfl_down(best, off);
    __shared__ float wsum[BLOCK / 64];
    if ((tid & 63) == 0) wsum[tid >> 6] = best;
    __syncthreads();
    if (tid == 0) {
        float s = 0.0f;
        #pragma unroll
        for (int w = 0; w < BLOCK / 64; ++w) s += wsum[w];
        partial[bid] = s;
    }
}

__global__ __launch_bounds__(512) void reduce_kernel(
    const float* __restrict__ partial, float* __restrict__ out)
{
    const int tid = threadIdx.x;
    float s = partial[tid];                // NBLOCKS = 512
    for (int off = 32; off > 0; off >>= 1) s += __shfl_down(s, off);
    __shared__ float wsum[8];
    if ((tid & 63) == 0) wsum[tid >> 6] = s;
    __syncthreads();
    if (tid == 0) {
        float t = 0.0f;
        #pragma unroll
        for (int w = 0; w < 8; ++w) t += wsum[w];
        *out = t * (1.0f / NGRIDS);
    }
}

extern "C" void kernel_launch(void* const* d_in, const int* in_sizes, int n_in,
                              void* d_out, int out_size, void* d_ws, size_t ws_size,
                              hipStream_t stream) {
    const float* pred = (const float*)d_in[0];  // inputs (1,1,512,512)
    const float* gt   = (const float*)d_in[1];  // targets (1,512,512)
    float* partial = (float*)d_ws;              // 512 floats
    float* out = (float*)d_out;
    chamfer_kernel<<<NBLOCKS, BLOCK, 0, stream>>>(pred, gt, partial);
    reduce_kernel<<<1, 512, 0, stream>>>(partial, out);
}

// Round 16
// 15.738 us; speedup vs baseline: 1.0326x; 1.0326x over previous
//
#include <hip/hip_runtime.h>

namespace {
constexpr int GS = 128;
constexpr int NPTS = GS * GS;          // 16384 points per grid
constexpr float RES = 0.25f;
constexpr int NGRIDS = 16;
constexpr int BLOCK = 1024;
constexpr int ROWS_PER_BLOCK = BLOCK / GS;     // 8 query rows per block
constexpr int CHUNKS = NPTS / BLOCK;           // 16 chunks per (grid,dir)
constexpr int NBLOCKS = NGRIDS * 2 * CHUNKS;   // 512
constexpr int SLAB_ROWS = 14;                  // max rows a block's windows touch
}

// FINAL: exact R13 configuration (best measured: 15.75 us; R15's za-hoist
// reverted — it cost ~0.5 us via register pressure across the staging loop).
// Session ledger: R1 brute force 757 us -> 48x via (1) radius-3 pruning with
// exact expanding-ring bound, (2) wave-cooperative straggler finish (the
// serial-tail fix, 41.8->17.2), (3) LDS slab staging (one latency exposure
// per block), (4) ds_read_b64 window reads. Remaining ~15.7 us is a
// source-invariant floor: every pipe <20% utilized; -56% LDS / -30% VALU /
// 4x WG-count changes all moved dur_us <1 us (R6/R8/R13 nulls).
// Phase A: 7-row x 8-col SUPERSET window (ds_read_b64 pairs) at clamped base
// — always in-grid, covers every in-grid cell at Chebyshev radius <= 3.
// Exact-done iff best <= (4*RES)^2 = 1.0. Phase B: wave-cooperative straggler
// scan from GLOBAL memory (~2e-5/query at thr=1.0; R11 proved tighter thr
// explodes the event rate); one pass with K >= ceil(sqrt(bestA)/RES) is exact
// (cells at Chebyshev radius >= K have planar >= (K*RES)^2 >= bestA).
__global__ __launch_bounds__(BLOCK, 8) void chamfer_kernel(
    const float* __restrict__ pred, const float* __restrict__ gt,
    float* __restrict__ partial)
{
    __shared__ float slab[SLAB_ROWS * GS];     // 7168 B

    const int bid = blockIdx.x;
    const int chunk = bid & (CHUNKS - 1);
    const int pair = bid >> 4;             // CHUNKS = 16
    const int g = pair >> 1;
    const int dir = pair & 1;
    const float* __restrict__ A  = (dir == 0) ? gt + g * NPTS : pred + g * NPTS;
    const float* __restrict__ DB = (dir == 0) ? pred + g * NPTS : gt + g * NPTS;

    const int tid = threadIdx.x;
    const int r0 = chunk * ROWS_PER_BLOCK;
    const int rlo = max(r0 - 3, 0);
    const int rhi = min(r0 + ROWS_PER_BLOCK + 2, GS - 1);  // r0+7 rows, +3 window
    const int nrow = rhi - rlo + 1;                        // <= 14

    // stage slab rows [rlo..rhi] as float4s: <=448 loads, fully coalesced
    if (tid < nrow * (GS / 4)) {
        const int row = tid >> 5;          // GS/4 = 32 quads per row
        const int c4  = tid & 31;
        reinterpret_cast<float4*>(slab)[tid] =
            reinterpret_cast<const float4*>(DB + (rlo + row) * GS)[c4];
    }
    __syncthreads();

    const int i = chunk * BLOCK + tid;
    const int ri = r0 + (tid >> 7);
    const int ci = tid & (GS - 1);
    const float za = A[i];

    // superset window: clamp the BASE, not each cell
    const int rb = min(max(ri, 3), GS - 4);
    const int cb = min(max(ci, 3), GS - 4);
    const int cE = min((cb - 3) & ~1, GS - 8);      // even, 8 cols all in-grid
    const float* __restrict__ wbase = slab + (rb - 3 - rlo) * GS + cE;

    // per-axis planar terms
    float dx2[7];
    #pragma unroll
    for (int t = 0; t < 7; ++t) {
        const float dx = (float)(ri - (rb - 3 + t)) * RES;
        dx2[t] = dx * dx;
    }
    float dy2[8];
    #pragma unroll
    for (int t = 0; t < 8; ++t) {
        const float dy = (float)(ci - (cE + t)) * RES;
        dy2[t] = dy * dy;
    }

    // phase A: 7 rows x 4 ds_read_b64 (8 cols); per-row min fold
    float bacc[4] = {1e30f, 1e30f, 1e30f, 1e30f};
    #pragma unroll
    for (int a = 0; a < 7; ++a) {
        const float2* rp = reinterpret_cast<const float2*>(wbase + a * GS);
        float rm0 = 1e30f, rm1 = 1e30f;
        #pragma unroll
        for (int t = 0; t < 4; ++t) {
            const float2 z2 = rp[t];                // ds_read_b64, imm offset
            const float d0 = za - z2.x;
            const float d1 = za - z2.y;
            rm0 = fminf(rm0, fmaf(d0, d0, dy2[2 * t]));
            rm1 = fminf(rm1, fmaf(d1, d1, dy2[2 * t + 1]));
        }
        bacc[a & 3] = fminf(bacc[a & 3], fminf(rm0, rm1) + dx2[a]);
    }
    float best = fminf(fminf(bacc[0], bacc[1]), fminf(bacc[2], bacc[3]));

    // phase B: wave-cooperative straggler finish (rare), from global
    const int lane = tid & 63;
    const int lr = lane >> 3, lc = lane & 7;   // 8x8 lane tile
    unsigned long long pend = __ballot(best > 1.0f);
    while (pend) {
        const int src = __ffsll(pend) - 1;
        pend &= pend - 1;
        const int qri = __shfl(ri, src);
        const int qci = __shfl(ci, src);
        const float qza = __shfl(za, src);
        const float qb  = __shfl(best, src);
        int K = (int)(4.0f * sqrtf(qb)) + 1;   // >= ceil(sqrt(qb)/RES)
        K = min(K, GS - 1);
        float m = 1e30f;
        for (int tr = -K; tr <= K; tr += 8) {
            const int dr = tr + lr;
            if (dr > K) continue;
            const int r = min(max(qri + dr, 0), GS - 1);
            const float dx = (float)(qri - r) * RES;
            const float dxx2 = dx * dx;
            const float* __restrict__ row = DB + r * GS;
            for (int tc = -K; tc <= K; tc += 8) {
                const int dc = tc + lc;
                if (dc > K) continue;
                const int c = min(max(qci + dc, 0), GS - 1);
                const float dy = (float)(qci - c) * RES;
                const float dz = qza - row[c];
                m = fminf(m, fmaf(dz, dz, fmaf(dy, dy, dxx2)));
            }
        }
        #pragma unroll
        for (int off = 32; off > 0; off >>= 1) m = fminf(m, __shfl_xor(m, off));
        if (lane == src) best = fminf(best, m);
    }

    // block sum-reduction -> one partial per block (no atomics)
    for (int off = 32; off > 0; off >>= 1) best += __shfl_down(best, off);
    __shared__ float wsum[BLOCK / 64];
    if ((tid & 63) == 0) wsum[tid >> 6] = best;
    __syncthreads();
    if (tid == 0) {
        float s = 0.0f;
        #pragma unroll
        for (int w = 0; w < BLOCK / 64; ++w) s += wsum[w];
        partial[bid] = s;
    }
}

__global__ __launch_bounds__(512) void reduce_kernel(
    const float* __restrict__ partial, float* __restrict__ out)
{
    const int tid = threadIdx.x;
    float s = partial[tid];                // NBLOCKS = 512
    for (int off = 32; off > 0; off >>= 1) s += __shfl_down(s, off);
    __shared__ float wsum[8];
    if ((tid & 63) == 0) wsum[tid >> 6] = s;
    __syncthreads();
    if (tid == 0) {
        float t = 0.0f;
        #pragma unroll
        for (int w = 0; w < 8; ++w) t += wsum[w];
        *out = t * (1.0f / NGRIDS);
    }
}

extern "C" void kernel_launch(void* const* d_in, const int* in_sizes, int n_in,
                              void* d_out, int out_size, void* d_ws, size_t ws_size,
                              hipStream_t stream) {
    const float* pred = (const float*)d_in[0];  // inputs (1,1,512,512)
    const float* gt   = (const float*)d_in[1];  // targets (1,512,512)
    float* partial = (float*)d_ws;              // 512 floats
    float* out = (float*)d_out;
    chamfer_kernel<<<NBLOCKS, BLOCK, 0, stream>>>(pred, gt, partial);
    reduce_kernel<<<1, 512, 0, stream>>>(partial, out);
}